// Round 13
// baseline (110.850 us; speedup 1.0000x reference)
//
#include <hip/hip_runtime.h>

#define N_FEAT 128
#define N_CLS 64
#define MAXD 96      // bucket capacity; true max in-deg ~35 for Binomial(800K,1/50K)
#define DSTRIDE 16   // deg padded to one counter per 64B line

// 0) zero padded degree counters + overflow count
__global__ __launch_bounds__(256) void k_zero(int4* __restrict__ p, int n4,
                                              int* __restrict__ ovf_cnt) {
    int i = blockIdx.x * blockDim.x + threadIdx.x;
    for (; i < n4; i += gridDim.x * blockDim.x) p[i] = make_int4(0, 0, 0, 0);
    if (blockIdx.x == 0 && threadIdx.x == 0) *ovf_cnt = 0;
}

// 1) FUSED: blocks [0, gemm_blocks) = GEMM Yraw = X @ W (wave-uniform W cols ->
//    s_load K$ broadcast). Remaining blocks = rank: 2 edges/thread (int2 loads,
//    2 independent atomic chains), coalesced int2 rank store.
__global__ __launch_bounds__(256) void k_fused(
    const float* __restrict__ X, const float* __restrict__ W, float* __restrict__ Y, int n,
    const int* __restrict__ dst, int ne, int* __restrict__ deg16, int* __restrict__ rank,
    int gemm_blocks) {
    int bid = blockIdx.x;
    if (bid < gemm_blocks) {
        int lane = threadIdx.x & 63;
        int q = __builtin_amdgcn_readfirstlane(threadIdx.x >> 6);  // wave 0..3
        int cq = q * 16;
        int node = bid * 64 + lane;
        if (node >= n) return;

        float acc[16];
#pragma unroll
        for (int c = 0; c < 16; ++c) acc[c] = 0.f;

        const float* xrow = X + (size_t)node * N_FEAT;
        const float* wq = W + cq;
        for (int k4 = 0; k4 < N_FEAT; k4 += 4) {
            float4 xv = *(const float4*)(xrow + k4);
#pragma unroll
            for (int j = 0; j < 4; ++j) {
                float xj = (j == 0) ? xv.x : (j == 1) ? xv.y : (j == 2) ? xv.z : xv.w;
                const float* wrow = wq + (size_t)(k4 + j) * N_CLS;  // wave-uniform
#pragma unroll
                for (int c = 0; c < 16; c += 4) {
                    float4 wv = *(const float4*)(wrow + c);
                    acc[c + 0] = fmaf(xj, wv.x, acc[c + 0]);
                    acc[c + 1] = fmaf(xj, wv.y, acc[c + 1]);
                    acc[c + 2] = fmaf(xj, wv.z, acc[c + 2]);
                    acc[c + 3] = fmaf(xj, wv.w, acc[c + 3]);
                }
            }
        }

        float* yrow = Y + (size_t)node * N_CLS + cq;
#pragma unroll
        for (int c = 0; c < 16; c += 4) {
            float4 o;
            o.x = acc[c + 0]; o.y = acc[c + 1]; o.z = acc[c + 2]; o.w = acc[c + 3];
            *(float4*)(yrow + c) = o;
        }
    } else {
        int e2 = ((bid - gemm_blocks) * 256 + threadIdx.x) * 2;
        if (e2 + 1 < ne) {
            int2 d = *(const int2*)(dst + e2);
            int p0 = atomicAdd(&deg16[d.x * DSTRIDE], 1);  // two independent chains
            int p1 = atomicAdd(&deg16[d.y * DSTRIDE], 1);
            *(int2*)(rank + e2) = make_int2(p0, p1);
        } else if (e2 < ne) {
            rank[e2] = atomicAdd(&deg16[dst[e2] * DSTRIDE], 1);
        }
    }
}

// 2) scatter (no atomics, independent load->store): slot[dst*MAXD+rank] = src
__global__ __launch_bounds__(256) void k_scatter(const int* __restrict__ src,
                                                 const int* __restrict__ dst,
                                                 const int* __restrict__ rank, int ne,
                                                 int* __restrict__ slot,
                                                 int* __restrict__ ovf,
                                                 int* __restrict__ ovf_cnt) {
    int e2 = (blockIdx.x * 256 + threadIdx.x) * 2;
#pragma unroll
    for (int j = 0; j < 2; ++j) {
        int i = e2 + j;
        if (i < ne) {
            int p = rank[i];
            if (p < MAXD) {
                slot[(size_t)dst[i] * MAXD + p] = src[i];
            } else {
                ovf[atomicAdd(ovf_cnt, 1)] = i;  // never expected; correctness gutter
            }
        }
    }
}

// 3) wave-per-dst gather over fixed-stride buckets; nrm computed on the fly:
//    out[d][c] = rsqrt(deg_d) * sum_p rsqrt(deg_sp) * Yraw[sp][c] + b[c]
__global__ __launch_bounds__(256) void k_agg(const int* __restrict__ deg16,
                                             const int* __restrict__ slot,
                                             const float* __restrict__ Y,
                                             const float* __restrict__ b,
                                             float* __restrict__ out, int n) {
    int wid = (int)((blockIdx.x * (size_t)blockDim.x + threadIdx.x) >> 6);
    if (wid >= n) return;
    int lane = threadIdx.x & 63;
    int g = lane >> 4;        // edge slot 0..3
    int c = (lane & 15) * 4;  // column base (16 lanes x float4 = full 64-col row)
    int dtrue = deg16[wid * DSTRIDE];  // wave-uniform broadcast load
    int dcnt = min(dtrue, MAXD);
    int s = wid * MAXD;
    int e = s + dcnt;
    float4 a0 = make_float4(0.f, 0.f, 0.f, 0.f);
    float4 a1 = make_float4(0.f, 0.f, 0.f, 0.f);
    int p = s + g;
    for (; p + 4 < e; p += 8) {
        int s0 = slot[p];
        int s1 = slot[p + 4];
        float f0 = rsqrtf(fmaxf((float)deg16[s0 * DSTRIDE], 1.0f));
        float f1 = rsqrtf(fmaxf((float)deg16[s1 * DSTRIDE], 1.0f));
        float4 r0 = *(const float4*)(Y + (size_t)s0 * N_CLS + c);
        float4 r1 = *(const float4*)(Y + (size_t)s1 * N_CLS + c);
        a0.x = fmaf(f0, r0.x, a0.x); a0.y = fmaf(f0, r0.y, a0.y);
        a0.z = fmaf(f0, r0.z, a0.z); a0.w = fmaf(f0, r0.w, a0.w);
        a1.x = fmaf(f1, r1.x, a1.x); a1.y = fmaf(f1, r1.y, a1.y);
        a1.z = fmaf(f1, r1.z, a1.z); a1.w = fmaf(f1, r1.w, a1.w);
    }
    if (p < e) {
        int s0 = slot[p];
        float f0 = rsqrtf(fmaxf((float)deg16[s0 * DSTRIDE], 1.0f));
        float4 r0 = *(const float4*)(Y + (size_t)s0 * N_CLS + c);
        a0.x = fmaf(f0, r0.x, a0.x); a0.y = fmaf(f0, r0.y, a0.y);
        a0.z = fmaf(f0, r0.z, a0.z); a0.w = fmaf(f0, r0.w, a0.w);
    }
    a0.x += a1.x; a0.y += a1.y; a0.z += a1.z; a0.w += a1.w;
#pragma unroll
    for (int m = 16; m <= 32; m <<= 1) {
        a0.x += __shfl_xor(a0.x, m);
        a0.y += __shfl_xor(a0.y, m);
        a0.z += __shfl_xor(a0.z, m);
        a0.w += __shfl_xor(a0.w, m);
    }
    if (lane < 16) {
        float nv = rsqrtf(fmaxf((float)dtrue, 1.0f));
        float4 bv = *(const float4*)(b + c);
        float4 o;
        o.x = a0.x * nv + bv.x;
        o.y = a0.y * nv + bv.y;
        o.z = a0.z * nv + bv.z;
        o.w = a0.w * nv + bv.w;
        *(float4*)(out + (size_t)wid * N_CLS + c) = o;
    }
}

// 4) overflow gutter (expected empty; single tiny block)
__global__ __launch_bounds__(64) void k_ovf(const int* __restrict__ ovf_cnt,
                                            const int* __restrict__ ovf,
                                            const int* __restrict__ src,
                                            const int* __restrict__ dst,
                                            const int* __restrict__ deg16,
                                            const float* __restrict__ Y,
                                            float* __restrict__ out) {
    int cnt = *ovf_cnt;
    for (int idx = 0; idx < cnt; ++idx) {
        int e = ovf[idx];
        int d = dst[e];
        int s = src[e];
        float f = rsqrtf(fmaxf((float)deg16[d * DSTRIDE], 1.0f)) *
                  rsqrtf(fmaxf((float)deg16[s * DSTRIDE], 1.0f));
        int c = threadIdx.x;  // 64 lanes = 64 cols
        atomicAdd(&out[(size_t)d * N_CLS + c], f * Y[(size_t)s * N_CLS + c]);
    }
}

extern "C" void kernel_launch(void* const* d_in, const int* in_sizes, int n_in,
                              void* d_out, int out_size, void* d_ws, size_t ws_size,
                              hipStream_t stream) {
    const float* X = (const float*)d_in[0];
    const float* W = (const float*)d_in[1];
    const float* b = (const float*)d_in[2];
    const int* src = (const int*)d_in[3];
    const int* dst = (const int*)d_in[4];
    int n = in_sizes[0] / N_FEAT;
    int ne = in_sizes[3];
    float* out = (float*)d_out;

    char* w = (char*)d_ws;
    auto take = [&](size_t bytes) {
        char* p = w;
        w += (bytes + 255) & ~(size_t)255;
        return p;
    };
    int* deg16 = (int*)take((size_t)n * DSTRIDE * 4);  // 3.2 MB padded counters
    int* slot = (int*)take((size_t)n * MAXD * 4);      // 19.2 MB buckets
    int* rank = (int*)take((size_t)ne * 4);
    int* ovf = (int*)take((size_t)4096 * 4);
    int* ovf_cnt = (int*)take(256);
    float* Y = (float*)take((size_t)n * N_CLS * 4);

    const int tb = 256;
    int n4 = (n * DSTRIDE) / 4;
    k_zero<<<1024, tb, 0, stream>>>((int4*)deg16, n4, ovf_cnt);

    int gemm_blocks = (n + 63) / 64;                   // 782
    int ne2 = (ne + 1) / 2;
    int rank_blocks = (ne2 + tb - 1) / tb;             // 1563
    k_fused<<<gemm_blocks + rank_blocks, tb, 0, stream>>>(X, W, Y, n, dst, ne, deg16, rank,
                                                          gemm_blocks);

    k_scatter<<<(ne2 + tb - 1) / tb, tb, 0, stream>>>(src, dst, rank, ne, slot, ovf, ovf_cnt);
    long long agg_threads = (long long)n * 64;
    k_agg<<<(int)((agg_threads + tb - 1) / tb), tb, 0, stream>>>(deg16, slot, Y, b, out, n);
    k_ovf<<<1, 64, 0, stream>>>(ovf_cnt, ovf, src, dst, deg16, Y, out);
}

// Round 14
// 94.727 us; speedup vs baseline: 1.1702x; 1.1702x over previous
//
#include <hip/hip_runtime.h>
#include <hip/hip_bf16.h>

#define N_FEAT 128
#define N_CLS 64
#define MAXD 96      // bucket capacity; true max in-deg ~35 for Binomial(800K,1/50K)
#define DSTRIDE 16   // deg padded to one counter per 64B line

// 0) zero padded degree counters + overflow count
__global__ __launch_bounds__(256) void k_zero(int4* __restrict__ p, int n4,
                                              int* __restrict__ ovf_cnt) {
    int i = blockIdx.x * blockDim.x + threadIdx.x;
    for (; i < n4; i += gridDim.x * blockDim.x) p[i] = make_int4(0, 0, 0, 0);
    if (blockIdx.x == 0 && threadIdx.x == 0) *ovf_cnt = 0;
}

// 1) FUSED: blocks [0, gemm_blocks) = GEMM Ybf = bf16(X @ W) (wave-uniform W cols
//    -> s_load K$ broadcast). Remaining blocks = rank (atomic histogram, 2/thread).
__global__ __launch_bounds__(256) void k_fused1(
    const float* __restrict__ X, const float* __restrict__ W, ushort* __restrict__ Ybf, int n,
    const int* __restrict__ dst, int ne, int* __restrict__ deg16, int* __restrict__ rank,
    int gemm_blocks) {
    int bid = blockIdx.x;
    if (bid < gemm_blocks) {
        int lane = threadIdx.x & 63;
        int q = __builtin_amdgcn_readfirstlane(threadIdx.x >> 6);  // wave 0..3
        int cq = q * 16;
        int node = bid * 64 + lane;
        if (node >= n) return;

        float acc[16];
#pragma unroll
        for (int c = 0; c < 16; ++c) acc[c] = 0.f;

        const float* xrow = X + (size_t)node * N_FEAT;
        const float* wq = W + cq;
        for (int k4 = 0; k4 < N_FEAT; k4 += 4) {
            float4 xv = *(const float4*)(xrow + k4);
#pragma unroll
            for (int j = 0; j < 4; ++j) {
                float xj = (j == 0) ? xv.x : (j == 1) ? xv.y : (j == 2) ? xv.z : xv.w;
                const float* wrow = wq + (size_t)(k4 + j) * N_CLS;  // wave-uniform
#pragma unroll
                for (int c = 0; c < 16; c += 4) {
                    float4 wv = *(const float4*)(wrow + c);
                    acc[c + 0] = fmaf(xj, wv.x, acc[c + 0]);
                    acc[c + 1] = fmaf(xj, wv.y, acc[c + 1]);
                    acc[c + 2] = fmaf(xj, wv.z, acc[c + 2]);
                    acc[c + 3] = fmaf(xj, wv.w, acc[c + 3]);
                }
            }
        }

        // RNE-convert 16 fp32 -> bf16, pack to 2x uint4, store 32B (16B-aligned)
        uint u[8];
#pragma unroll
        for (int h = 0; h < 8; ++h) {
            __hip_bfloat16 lo = __float2bfloat16(acc[2 * h]);
            __hip_bfloat16 hi = __float2bfloat16(acc[2 * h + 1]);
            ushort ulo = *(ushort*)&lo;
            ushort uhi = *(ushort*)&hi;
            u[h] = ((uint)uhi << 16) | ulo;
        }
        ushort* yrow = Ybf + (size_t)node * N_CLS + cq;
        *(uint4*)(yrow + 0) = make_uint4(u[0], u[1], u[2], u[3]);
        *(uint4*)(yrow + 8) = make_uint4(u[4], u[5], u[6], u[7]);
    } else {
        int e2 = ((bid - gemm_blocks) * 256 + threadIdx.x) * 2;
        if (e2 + 1 < ne) {
            int2 d = *(const int2*)(dst + e2);
            int p0 = atomicAdd(&deg16[d.x * DSTRIDE], 1);  // two independent chains
            int p1 = atomicAdd(&deg16[d.y * DSTRIDE], 1);
            *(int2*)(rank + e2) = make_int2(p0, p1);
        } else if (e2 < ne) {
            rank[e2] = atomicAdd(&deg16[dst[e2] * DSTRIDE], 1);
        }
    }
}

// 2) FUSED: scatter blocks (slot[dst*MAXD+rank]=src, no atomics) ∥ nrm blocks
//    (dense nrm[i] = rsqrt(max(deg,1)) -> 200KB, L2-resident for agg's gathers)
__global__ __launch_bounds__(256) void k_fused2(
    const int* __restrict__ src, const int* __restrict__ dst, const int* __restrict__ rank,
    int ne, int* __restrict__ slot, int* __restrict__ ovf, int* __restrict__ ovf_cnt,
    const int* __restrict__ deg16, int n, float* __restrict__ nrm, int scat_blocks) {
    int bid = blockIdx.x;
    if (bid < scat_blocks) {
        int e2 = (bid * 256 + threadIdx.x) * 2;
#pragma unroll
        for (int j = 0; j < 2; ++j) {
            int i = e2 + j;
            if (i < ne) {
                int p = rank[i];
                if (p < MAXD) {
                    slot[(size_t)dst[i] * MAXD + p] = src[i];
                } else {
                    ovf[atomicAdd(ovf_cnt, 1)] = i;  // never expected; gutter
                }
            }
        }
    } else {
        int i = (bid - scat_blocks) * 256 + threadIdx.x;
        if (i < n) nrm[i] = rsqrtf(fmaxf((float)deg16[i * DSTRIDE], 1.0f));
    }
}

// 3) wave-per-dst gather over buckets, bf16 Y rows (128B/row), dense nrm:
//    out[d][c] = nrm[d] * sum_p nrm[slot_p] * Ybf[slot_p][c] + b[c]
__global__ __launch_bounds__(256) void k_agg(const int* __restrict__ deg16,
                                             const int* __restrict__ slot,
                                             const ushort* __restrict__ Ybf,
                                             const float* __restrict__ nrm,
                                             const float* __restrict__ b,
                                             float* __restrict__ out, int n) {
    int wid = (int)((blockIdx.x * (size_t)blockDim.x + threadIdx.x) >> 6);
    if (wid >= n) return;
    int lane = threadIdx.x & 63;
    int g = lane >> 4;        // edge slot 0..3
    int c = (lane & 15) * 4;  // column base (16 lanes x 4 cols = 64)
    int dtrue = deg16[wid * DSTRIDE];  // wave-uniform broadcast load
    int dcnt = min(dtrue, MAXD);
    int s = wid * MAXD;
    int e = s + dcnt;
    float a0x = 0.f, a0y = 0.f, a0z = 0.f, a0w = 0.f;
    float a1x = 0.f, a1y = 0.f, a1z = 0.f, a1w = 0.f;
    int p = s + g;
    for (; p + 4 < e; p += 8) {
        int s0 = slot[p];
        int s1 = slot[p + 4];
        float f0 = nrm[s0];
        float f1 = nrm[s1];
        uint2 v0 = *(const uint2*)(Ybf + (size_t)s0 * N_CLS + c);  // 4 bf16 cols
        uint2 v1 = *(const uint2*)(Ybf + (size_t)s1 * N_CLS + c);
        a0x = fmaf(f0, __uint_as_float(v0.x << 16), a0x);
        a0y = fmaf(f0, __uint_as_float(v0.x & 0xFFFF0000u), a0y);
        a0z = fmaf(f0, __uint_as_float(v0.y << 16), a0z);
        a0w = fmaf(f0, __uint_as_float(v0.y & 0xFFFF0000u), a0w);
        a1x = fmaf(f1, __uint_as_float(v1.x << 16), a1x);
        a1y = fmaf(f1, __uint_as_float(v1.x & 0xFFFF0000u), a1y);
        a1z = fmaf(f1, __uint_as_float(v1.y << 16), a1z);
        a1w = fmaf(f1, __uint_as_float(v1.y & 0xFFFF0000u), a1w);
    }
    if (p < e) {
        int s0 = slot[p];
        float f0 = nrm[s0];
        uint2 v0 = *(const uint2*)(Ybf + (size_t)s0 * N_CLS + c);
        a0x = fmaf(f0, __uint_as_float(v0.x << 16), a0x);
        a0y = fmaf(f0, __uint_as_float(v0.x & 0xFFFF0000u), a0y);
        a0z = fmaf(f0, __uint_as_float(v0.y << 16), a0z);
        a0w = fmaf(f0, __uint_as_float(v0.y & 0xFFFF0000u), a0w);
    }
    a0x += a1x; a0y += a1y; a0z += a1z; a0w += a1w;
#pragma unroll
    for (int m = 16; m <= 32; m <<= 1) {
        a0x += __shfl_xor(a0x, m);
        a0y += __shfl_xor(a0y, m);
        a0z += __shfl_xor(a0z, m);
        a0w += __shfl_xor(a0w, m);
    }
    if (lane < 16) {
        float nv = nrm[wid];
        float4 bv = *(const float4*)(b + c);
        float4 o;
        o.x = a0x * nv + bv.x;
        o.y = a0y * nv + bv.y;
        o.z = a0z * nv + bv.z;
        o.w = a0w * nv + bv.w;
        *(float4*)(out + (size_t)wid * N_CLS + c) = o;
    }
}

// 4) overflow gutter (expected empty; single tiny block)
__global__ __launch_bounds__(64) void k_ovf(const int* __restrict__ ovf_cnt,
                                            const int* __restrict__ ovf,
                                            const int* __restrict__ src,
                                            const int* __restrict__ dst,
                                            const float* __restrict__ nrm,
                                            const ushort* __restrict__ Ybf,
                                            float* __restrict__ out) {
    int cnt = *ovf_cnt;
    for (int idx = 0; idx < cnt; ++idx) {
        int e = ovf[idx];
        int d = dst[e];
        int s = src[e];
        float f = nrm[d] * nrm[s];
        int c = threadIdx.x;  // 64 lanes = 64 cols
        float y = __uint_as_float(((uint)Ybf[(size_t)s * N_CLS + c]) << 16);
        atomicAdd(&out[(size_t)d * N_CLS + c], f * y);
    }
}

extern "C" void kernel_launch(void* const* d_in, const int* in_sizes, int n_in,
                              void* d_out, int out_size, void* d_ws, size_t ws_size,
                              hipStream_t stream) {
    const float* X = (const float*)d_in[0];
    const float* W = (const float*)d_in[1];
    const float* b = (const float*)d_in[2];
    const int* src = (const int*)d_in[3];
    const int* dst = (const int*)d_in[4];
    int n = in_sizes[0] / N_FEAT;
    int ne = in_sizes[3];
    float* out = (float*)d_out;

    char* w = (char*)d_ws;
    auto take = [&](size_t bytes) {
        char* p = w;
        w += (bytes + 255) & ~(size_t)255;
        return p;
    };
    int* deg16 = (int*)take((size_t)n * DSTRIDE * 4);  // 3.2 MB padded counters
    int* slot = (int*)take((size_t)n * MAXD * 4);      // 19.2 MB buckets
    int* rank = (int*)take((size_t)ne * 4);
    int* ovf = (int*)take((size_t)4096 * 4);
    int* ovf_cnt = (int*)take(256);
    float* nrm = (float*)take((size_t)n * 4);
    ushort* Ybf = (ushort*)take((size_t)n * N_CLS * 2);  // 6.4 MB bf16 Y

    const int tb = 256;
    int n4 = (n * DSTRIDE) / 4;
    k_zero<<<1024, tb, 0, stream>>>((int4*)deg16, n4, ovf_cnt);

    int gemm_blocks = (n + 63) / 64;        // 782
    int ne2 = (ne + 1) / 2;
    int rank_blocks = (ne2 + tb - 1) / tb;  // 1563
    k_fused1<<<gemm_blocks + rank_blocks, tb, 0, stream>>>(X, W, Ybf, n, dst, ne, deg16, rank,
                                                           gemm_blocks);

    int scat_blocks = (ne2 + tb - 1) / tb;  // 1563
    int nrm_blocks = (n + tb - 1) / tb;     // 196
    k_fused2<<<scat_blocks + nrm_blocks, tb, 0, stream>>>(src, dst, rank, ne, slot, ovf,
                                                          ovf_cnt, deg16, n, nrm, scat_blocks);

    long long agg_threads = (long long)n * 64;
    k_agg<<<(int)((agg_threads + tb - 1) / tb), tb, 0, stream>>>(deg16, slot, Ybf, nrm, b, out,
                                                                 n);
    k_ovf<<<1, 64, 0, stream>>>(ovf_cnt, ovf, src, dst, nrm, Ybf, out);
}